// Round 1
// baseline (9925.195 us; speedup 1.0000x reference)
//
#include <hip/hip_runtime.h>

#define T_STEPS 101
#define BATCH   16384
#define IN_DIM  40
#define HID     300
#define OUT_DIM 12

#define RPW 8            // rows per wave
#define WPB 4            // waves per block
#define RPB (RPW * WPB)  // 32 rows per block

// ---- ws layout (floats) ----
// [0, 90000)        WhT[i][j]  = Wh[j][i]   (column i of Wh, contiguous)
// [90000, 180000)   W2T[i][j]  = W2[j][i]
// [180000, 183600)  W3T[i][o]  = W3[o][i]
#define WS_W2T 90000
#define WS_W3T 180000

__global__ __launch_bounds__(256) void prep_kernel(const float* __restrict__ Wh,
                                                   const float* __restrict__ W2,
                                                   const float* __restrict__ W3,
                                                   float* __restrict__ ws) {
    int idx = blockIdx.x * 256 + threadIdx.x;
    if (idx < 90000) {
        int i = idx / 300, j = idx % 300;
        ws[idx] = Wh[j * 300 + i];
    } else if (idx < 180000) {
        int k = idx - 90000;
        int i = k / 300, j = k % 300;
        ws[idx] = W2[j * 300 + i];
    } else if (idx < 183600) {
        int k = idx - 180000;
        int i = k / 12, j = k % 12;
        ws[idx] = W3[j * 300 + i];
    }
}

__global__ __launch_bounds__(256, 2) void snn_kernel(
    const float* __restrict__ x,    // [T, B, 40]
    const float* __restrict__ W1,   // [300, 40]
    const float* __restrict__ b1,   // [300]
    const float* __restrict__ bh,   // [300]
    const float* __restrict__ b2,   // [300]
    const float* __restrict__ b3,   // [12]
    const float* __restrict__ ws,   // transposed weights
    float* __restrict__ out)        // [B, 12]
{
    // LDS: W1 chunked layout w1c[kc][j][c] = W1[j][4*kc + c], j padded to 320.
    // Lane reads float4 at (kc*320 + j)*4 -> consecutive lanes stride 16B: conflict-free.
    __shared__ float w1c[10 * 320 * 4];                 // 51200 B
    __shared__ float xb[2][RPB][IN_DIM];                // 10240 B
    __shared__ unsigned long long msk[RPB][5];          // 1280 B (layer-1 spike masks)
    __shared__ float oacc[RPB][OUT_DIM];                // 1536 B

    const int tid  = threadIdx.x;
    const int lane = tid & 63;
    const int wv   = tid >> 6;
    const int row0 = blockIdx.x * RPB;

    // ---- stage W1 into chunked LDS layout (pad rows 300..319 with zeros) ----
    for (int idx = tid; idx < 3200; idx += 256) {
        int kc = idx % 10;
        int j  = idx / 10;
        float4 v;
        if (j < HID) v = *(const float4*)(W1 + j * IN_DIM + kc * 4);
        else         v = make_float4(0.f, 0.f, 0.f, 0.f);
        *(float4*)(w1c + (kc * 320 + j) * 4) = v;
    }
    // zero masks (y0 = 0) and output accumulators
    for (int idx = tid; idx < RPB * 5; idx += 256) ((unsigned long long*)msk)[idx] = 0ull;
    for (int idx = tid; idx < RPB * OUT_DIM; idx += 256) ((float*)oacc)[idx] = 0.f;
    // stage x[t=0]
    {
        const float4* src = (const float4*)(x + (size_t)row0 * IN_DIM);
        float4* dst = (float4*)&xb[0][0][0];
        for (int idx = tid; idx < RPB * IN_DIM / 4; idx += 256) dst[idx] = src[idx];
    }

    // per-lane bias registers for its 5 neurons j = lane + 64u
    float b1h[5], b2r[5];
#pragma unroll
    for (int u = 0; u < 5; ++u) {
        int j = lane + 64 * u;
        b1h[u] = (j < HID) ? (b1[j] + bh[j]) : 0.f;
        b2r[u] = (j < HID) ? b2[j] : 0.f;
    }

    const float* WhT = ws;
    const float* W2T = ws + WS_W2T;
    const float* W3T = ws + WS_W3T;

    float v1[RPW][5], v2[RPW][5];
#pragma unroll
    for (int r = 0; r < RPW; ++r)
#pragma unroll
        for (int u = 0; u < 5; ++u) { v1[r][u] = 0.f; v2[r][u] = 0.f; }

    __syncthreads();

    const unsigned long long TAILMASK = (1ull << 44) - 1ull;  // 44 valid lanes at u=4

    for (int t = 0; t < T_STEPS; ++t) {
        // ---- stage next step's x into the other buffer ----
        if (t + 1 < T_STEPS) {
            const float4* src = (const float4*)(x + (size_t)(t + 1) * BATCH * IN_DIM
                                                  + (size_t)row0 * IN_DIM);
            float4* dst = (float4*)&xb[(t + 1) & 1][0][0];
            for (int idx = tid; idx < RPB * IN_DIM / 4; idx += 256) dst[idx] = src[idx];
        }
        const float(*xc)[IN_DIM] = xb[t & 1];

        // ---- h1 = x @ W1^T + (b1 + bh), for this wave's RPW rows ----
        float acc[RPW][5];
#pragma unroll
        for (int r = 0; r < RPW; ++r)
#pragma unroll
            for (int u = 0; u < 5; ++u) acc[r][u] = b1h[u];

#pragma unroll
        for (int kc = 0; kc < 10; ++kc) {
            float4 w[5];
#pragma unroll
            for (int u = 0; u < 5; ++u)
                w[u] = *(const float4*)(w1c + (kc * 320 + lane + 64 * u) * 4);
#pragma unroll
            for (int r = 0; r < RPW; ++r) {
                float4 xv = *(const float4*)(&xc[wv * RPW + r][kc * 4]);
#pragma unroll
                for (int u = 0; u < 5; ++u) {
                    float a = acc[r][u];
                    a = fmaf(w[u].x, xv.x, a);
                    a = fmaf(w[u].y, xv.y, a);
                    a = fmaf(w[u].z, xv.z, a);
                    a = fmaf(w[u].w, xv.w, a);
                    acc[r][u] = a;
                }
            }
        }

        // ---- per-row LIF dynamics ----
#pragma unroll
        for (int r = 0; r < RPW; ++r) {
            const int lr = wv * RPW + r;

            float cur[5];
#pragma unroll
            for (int u = 0; u < 5; ++u) cur[u] = acc[r][u];

            // recurrent input: y_{t-1} @ Wh^T  (sparse column adds)
#pragma unroll
            for (int u2 = 0; u2 < 5; ++u2) {
                unsigned long long m = msk[lr][u2];  // wave-uniform
                while (m) {
                    int b = __builtin_ctzll(m);
                    m &= m - 1;
                    const float* wr = WhT + (u2 * 64 + b) * 300 + lane;
#pragma unroll
                    for (int u = 0; u < 5; ++u) cur[u] += wr[64 * u];
                }
            }

            // LIF layer 1: v <- v + (cur - v)/2 ; spike ; hard reset
            unsigned long long nm[5];
#pragma unroll
            for (int u = 0; u < 5; ++u) {
                float v = v1[r][u];
                v = v + (cur[u] - v) * 0.5f;
                bool s = (v >= 1.0f);
                v1[r][u] = s ? 0.f : v;
                nm[u] = __ballot(s);
            }
            nm[4] &= TAILMASK;

            // store masks for next step's recurrence (wave-private region)
            if (lane == 0) {
#pragma unroll
                for (int u = 0; u < 5; ++u) msk[lr][u] = nm[u];
            }

            // layer 2: cur2 = y @ W2^T + b2 (sparse)
            float c2[5];
#pragma unroll
            for (int u = 0; u < 5; ++u) c2[u] = b2r[u];
#pragma unroll
            for (int u2 = 0; u2 < 5; ++u2) {
                unsigned long long m = nm[u2];
                while (m) {
                    int b = __builtin_ctzll(m);
                    m &= m - 1;
                    const float* wr = W2T + (u2 * 64 + b) * 300 + lane;
#pragma unroll
                    for (int u = 0; u < 5; ++u) c2[u] += wr[64 * u];
                }
            }

            // LIF layer 2 + output accumulation (s2 spikes are very rare)
            unsigned long long sm[5];
#pragma unroll
            for (int u = 0; u < 5; ++u) {
                float v = v2[r][u];
                v = v + (c2[u] - v) * 0.5f;
                bool s = (v >= 1.0f);
                v2[r][u] = s ? 0.f : v;
                sm[u] = __ballot(s);
            }
            sm[4] &= TAILMASK;
#pragma unroll
            for (int u2 = 0; u2 < 5; ++u2) {
                unsigned long long m = sm[u2];
                while (m) {
                    int b = __builtin_ctzll(m);
                    m &= m - 1;
                    if (lane < OUT_DIM)
                        oacc[lr][lane] += W3T[(u2 * 64 + b) * OUT_DIM + lane];
                }
            }
        }
        __syncthreads();
    }

    // ---- epilogue: out = oacc + 101 * b3 ----
    for (int idx = tid; idx < RPB * OUT_DIM; idx += 256) {
        int r = idx / OUT_DIM, o = idx % OUT_DIM;
        out[(size_t)(row0 + r) * OUT_DIM + o] = oacc[r][o] + 101.0f * b3[o];
    }
}

extern "C" void kernel_launch(void* const* d_in, const int* in_sizes, int n_in,
                              void* d_out, int out_size, void* d_ws, size_t ws_size,
                              hipStream_t stream) {
    const float* x  = (const float*)d_in[0];
    const float* W1 = (const float*)d_in[1];
    const float* b1 = (const float*)d_in[2];
    const float* Wh = (const float*)d_in[3];
    const float* bh = (const float*)d_in[4];
    const float* W2 = (const float*)d_in[5];
    const float* b2 = (const float*)d_in[6];
    const float* W3 = (const float*)d_in[7];
    const float* b3 = (const float*)d_in[8];
    float* out = (float*)d_out;
    float* ws  = (float*)d_ws;

    // transpose Wh, W2, W3 into ws (needs 183600 floats = 734.4 KB)
    prep_kernel<<<(183600 + 255) / 256, 256, 0, stream>>>(Wh, W2, W3, ws);

    // persistent scan: 512 blocks x 256 threads, each wave owns 8 batch rows
    snn_kernel<<<BATCH / RPB, 256, 0, stream>>>(x, W1, b1, bh, b2, b3, ws, out);
}

// Round 2
// 8488.792 us; speedup vs baseline: 1.1692x; 1.1692x over previous
//
#include <hip/hip_runtime.h>

#define T_STEPS 101
#define BATCH   16384
#define IN_DIM  40
#define HID     300
#define OUT_DIM 12

#define RPW 8            // rows per wave
#define WPB 4            // waves per block
#define RPB (RPW * WPB)  // 32 rows per block

// ---- ws layout (floats) ----
// [0, 96000)         WhT[i][j] = Wh[j][i], column stride 320 (j in [300,320) = 0)
// [96000, 192000)    W2T[i][j] = W2[j][i], column stride 320
// [192000, 195600)   W3T[i][o] = W3[o][i], stride 12
#define WS_W2T 96000
#define WS_W3T 192000

// compile-time unroll helper: guarantees constexpr indices even when the
// loop body contains data-dependent while-loops (plain #pragma unroll bailed
// out in round 1 -> dynamic alloca indexing -> 39 GB of scratch traffic).
template<int I> struct ic { static constexpr int v = I; };
template<int N, int I = 0, typename F>
__device__ __forceinline__ void sfor(F&& f) {
    if constexpr (I < N) {
        f(ic<I>{});
        sfor<N, I + 1, F>(static_cast<F&&>(f));
    }
}

__global__ __launch_bounds__(256) void prep_kernel(const float* __restrict__ Wh,
                                                   const float* __restrict__ W2,
                                                   const float* __restrict__ W3,
                                                   float* __restrict__ ws) {
    int idx = blockIdx.x * 256 + threadIdx.x;
    if (idx < 96000) {
        int i = idx / 320, j = idx % 320;
        ws[idx] = (j < HID) ? Wh[j * HID + i] : 0.f;
    } else if (idx < 192000) {
        int k = idx - 96000;
        int i = k / 320, j = k % 320;
        ws[idx] = (j < HID) ? W2[j * HID + i] : 0.f;
    } else if (idx < 195600) {
        int k = idx - 192000;
        int i = k / OUT_DIM, j = k % OUT_DIM;
        ws[idx] = W3[j * HID + i];
    }
}

__global__ __launch_bounds__(256, 2) void snn_kernel(
    const float* __restrict__ x,    // [T, B, 40]
    const float* __restrict__ W1,   // [300, 40]
    const float* __restrict__ b1,   // [300]
    const float* __restrict__ bh,   // [300]
    const float* __restrict__ b2,   // [300]
    const float* __restrict__ b3,   // [12]
    const float* __restrict__ ws,   // transposed/padded weights
    float* __restrict__ out)        // [B, 12]
{
    // w1c[kc][j][c] = W1[j][4*kc+c], j padded to 320 (zeros). Lane reads
    // float4 at (kc*320 + j)*4 -> 16B stride across lanes: conflict-free.
    __shared__ float w1c[10 * 320 * 4];                 // 51200 B
    __shared__ unsigned long long msk[RPB][5];          // layer-1 spike masks
    __shared__ float oacc[RPB][OUT_DIM];

    const int tid  = threadIdx.x;
    const int lane = tid & 63;
    const int wv   = __builtin_amdgcn_readfirstlane(tid >> 6);  // wave-uniform
    const int row0 = blockIdx.x * RPB;

    // ---- stage W1 into chunked LDS layout ----
    for (int idx = tid; idx < 3200; idx += 256) {
        int kc = idx % 10;
        int j  = idx / 10;
        float4 v;
        if (j < HID) v = *(const float4*)(W1 + j * IN_DIM + kc * 4);
        else         v = make_float4(0.f, 0.f, 0.f, 0.f);
        *(float4*)(w1c + (kc * 320 + j) * 4) = v;
    }
    for (int idx = tid; idx < RPB * 5; idx += 256) ((unsigned long long*)msk)[idx] = 0ull;
    for (int idx = tid; idx < RPB * OUT_DIM; idx += 256) ((float*)oacc)[idx] = 0.f;

    // per-lane biases for neurons j = lane + 64u (tail j>=300 -> 0)
    float b1h[5], b2r[5];
    sfor<5>([&](auto uc) {
        constexpr int u = decltype(uc)::v;
        int j = lane + 64 * u;
        b1h[u] = (j < HID) ? (b1[j] + bh[j]) : 0.f;
        b2r[u] = (j < HID) ? b2[j] : 0.f;
    });

    const float* WhT = ws;
    const float* W2T = ws + WS_W2T;
    const float* W3T = ws + WS_W3T;

    float v1[RPW][5], v2[RPW][5];
    sfor<RPW>([&](auto rc) {
        constexpr int r = decltype(rc)::v;
        sfor<5>([&](auto uc) {
            constexpr int u = decltype(uc)::v;
            v1[r][u] = 0.f; v2[r][u] = 0.f;
        });
    });

    __syncthreads();

    const unsigned long long TAILMASK = (1ull << 44) - 1ull;  // 44 valid lanes at u=4

    for (int t = 0; t < T_STEPS; ++t) {
        // wave-uniform base for this wave's 8 rows at step t
        const float* xt = x + ((size_t)t * BATCH + row0 + wv * RPW) * IN_DIM;

        // ---- h1 = x @ W1^T + (b1 + bh) ----
        float acc[RPW][5];
        sfor<RPW>([&](auto rc) {
            constexpr int r = decltype(rc)::v;
            sfor<5>([&](auto uc) {
                constexpr int u = decltype(uc)::v;
                acc[r][u] = b1h[u];
            });
        });

        sfor<10>([&](auto kcc) {
            constexpr int kc = decltype(kcc)::v;
            float4 w[5];
            sfor<5>([&](auto uc) {
                constexpr int u = decltype(uc)::v;
                w[u] = *(const float4*)(w1c + (kc * 320 + lane + 64 * u) * 4);
            });
            sfor<RPW>([&](auto rc) {
                constexpr int r = decltype(rc)::v;
                const float* xr = xt + r * IN_DIM + kc * 4;   // uniform -> s_load
                float x0 = xr[0], x1 = xr[1], x2 = xr[2], x3 = xr[3];
                sfor<5>([&](auto uc) {
                    constexpr int u = decltype(uc)::v;
                    float a = acc[r][u];
                    a = fmaf(w[u].x, x0, a);
                    a = fmaf(w[u].y, x1, a);
                    a = fmaf(w[u].z, x2, a);
                    a = fmaf(w[u].w, x3, a);
                    acc[r][u] = a;
                });
            });
        });

        // ---- per-row LIF dynamics ----
        sfor<RPW>([&](auto rc) {
            constexpr int r = decltype(rc)::v;
            const int lr = wv * RPW + r;

            float cur[5];
            sfor<5>([&](auto uc) {
                constexpr int u = decltype(uc)::v;
                cur[u] = acc[r][u];
            });

            // recurrent input: y_{t-1} @ Wh^T (sparse column adds)
            sfor<5>([&](auto u2c) {
                constexpr int u2 = decltype(u2c)::v;
                unsigned long long m = msk[lr][u2];   // wave-uniform, wave-private
                while (m) {
                    int b = __builtin_ctzll(m);
                    m &= m - 1;
                    const float* wr = WhT + (u2 * 64 + b) * 320 + lane;
                    sfor<5>([&](auto uc) {
                        constexpr int u = decltype(uc)::v;
                        cur[u] += wr[64 * u];
                    });
                }
            });

            // LIF layer 1: v += (cur - v)/2 ; spike ; hard reset
            unsigned long long nm[5];
            sfor<5>([&](auto uc) {
                constexpr int u = decltype(uc)::v;
                float v = v1[r][u];
                v = v + (cur[u] - v) * 0.5f;
                bool s = (v >= 1.0f);
                v1[r][u] = s ? 0.f : v;
                nm[u] = __ballot(s);
            });
            nm[4] &= TAILMASK;

            if (lane == 0) {
                sfor<5>([&](auto uc) {
                    constexpr int u = decltype(uc)::v;
                    msk[lr][u] = nm[u];
                });
            }

            // layer 2: cur2 = y @ W2^T + b2 (sparse)
            float c2[5];
            sfor<5>([&](auto uc) {
                constexpr int u = decltype(uc)::v;
                c2[u] = b2r[u];
            });
            sfor<5>([&](auto u2c) {
                constexpr int u2 = decltype(u2c)::v;
                unsigned long long m = nm[u2];
                while (m) {
                    int b = __builtin_ctzll(m);
                    m &= m - 1;
                    const float* wr = W2T + (u2 * 64 + b) * 320 + lane;
                    sfor<5>([&](auto uc) {
                        constexpr int u = decltype(uc)::v;
                        c2[u] += wr[64 * u];
                    });
                }
            });

            // LIF layer 2 + output accumulation (s2 spikes are very rare)
            unsigned long long sm[5];
            sfor<5>([&](auto uc) {
                constexpr int u = decltype(uc)::v;
                float v = v2[r][u];
                v = v + (c2[u] - v) * 0.5f;
                bool s = (v >= 1.0f);
                v2[r][u] = s ? 0.f : v;
                sm[u] = __ballot(s);
            });
            sm[4] &= TAILMASK;
            sfor<5>([&](auto u2c) {
                constexpr int u2 = decltype(u2c)::v;
                unsigned long long m = sm[u2];
                while (m) {
                    int b = __builtin_ctzll(m);
                    m &= m - 1;
                    if (lane < OUT_DIM)
                        oacc[lr][lane] += W3T[(u2 * 64 + b) * OUT_DIM + lane];
                }
            });
        });
    }

    __syncthreads();

    // ---- epilogue: out = oacc + 101 * b3 ----
    for (int idx = tid; idx < RPB * OUT_DIM; idx += 256) {
        int r = idx / OUT_DIM, o = idx % OUT_DIM;
        out[(size_t)(row0 + r) * OUT_DIM + o] = oacc[r][o] + 101.0f * b3[o];
    }
}

extern "C" void kernel_launch(void* const* d_in, const int* in_sizes, int n_in,
                              void* d_out, int out_size, void* d_ws, size_t ws_size,
                              hipStream_t stream) {
    const float* x  = (const float*)d_in[0];
    const float* W1 = (const float*)d_in[1];
    const float* b1 = (const float*)d_in[2];
    const float* Wh = (const float*)d_in[3];
    const float* bh = (const float*)d_in[4];
    const float* W2 = (const float*)d_in[5];
    const float* b2 = (const float*)d_in[6];
    const float* W3 = (const float*)d_in[7];
    const float* b3 = (const float*)d_in[8];
    float* out = (float*)d_out;
    float* ws  = (float*)d_ws;

    prep_kernel<<<(195600 + 255) / 256, 256, 0, stream>>>(Wh, W2, W3, ws);
    snn_kernel<<<BATCH / RPB, 256, 0, stream>>>(x, W1, b1, bh, b2, b3, ws, out);
}

// Round 3
// 7467.670 us; speedup vs baseline: 1.3291x; 1.1367x over previous
//
#include <hip/hip_runtime.h>

#define T_STEPS 101
#define BATCH   16384
#define IN_DIM  40
#define HID     300
#define OUT_DIM 12

#define RPW 8            // rows per wave
#define WPB 4            // waves per block
#define RPB (RPW * WPB)  // 32 rows per block

// ---- ws layout (floats) ----
// [0, 96000)         WhT[i][j] = Wh[j][i], column stride 320 (j in [300,320) = 0)
// [96000, 192000)    W2T[i][j] = W2[j][i], column stride 320
// [192000, 195600)   W3T[i][o] = W3[o][i], stride 12
#define WS_W2T 96000
#define WS_W3T 192000

// compile-time unroll helper: guarantees constexpr indices even when the
// loop body contains data-dependent while-loops (round-1 lesson: plain
// #pragma unroll bails -> dynamic alloca -> scratch traffic).
template<int I> struct ic { static constexpr int v = I; };
template<int N, int I = 0, typename F>
__device__ __forceinline__ void sfor(F&& f) {
    if constexpr (I < N) {
        f(ic<I>{});
        sfor<N, I + 1, F>(static_cast<F&&>(f));
    }
}

__global__ __launch_bounds__(256) void prep_kernel(const float* __restrict__ Wh,
                                                   const float* __restrict__ W2,
                                                   const float* __restrict__ W3,
                                                   float* __restrict__ ws) {
    int idx = blockIdx.x * 256 + threadIdx.x;
    if (idx < 96000) {
        int i = idx / 320, j = idx % 320;
        ws[idx] = (j < HID) ? Wh[j * HID + i] : 0.f;
    } else if (idx < 192000) {
        int k = idx - 96000;
        int i = k / 320, j = k % 320;
        ws[idx] = (j < HID) ? W2[j * HID + i] : 0.f;
    } else if (idx < 195600) {
        int k = idx - 192000;
        int i = k / OUT_DIM, j = k % OUT_DIM;
        ws[idx] = W3[j * HID + i];
    }
}

// launch_bounds(256, 1): round-2's (256,2) made the allocator cap at 128
// VGPRs and spill ~20 regs/thread/step -> 1 GB scratch writes + L2 thrash.
// Demand is ~200 VGPRs; budget 512 -> no spill, 2 waves/SIMD.
__global__ __launch_bounds__(256, 1) void snn_kernel(
    const float* __restrict__ x,    // [T, B, 40]
    const float* __restrict__ W1,   // [300, 40]
    const float* __restrict__ b1,   // [300]
    const float* __restrict__ bh,   // [300]
    const float* __restrict__ b2,   // [300]
    const float* __restrict__ b3,   // [12]
    const float* __restrict__ ws,   // transposed/padded weights
    float* __restrict__ out)        // [B, 12]
{
    // w1c[kc][j][c] = W1[j][4*kc+c], j padded to 320 (zeros). Lane reads
    // float4 at (kc*320 + j)*4 -> 16B stride across lanes: conflict-free.
    __shared__ float w1c[10 * 320 * 4];                 // 51200 B
    __shared__ unsigned long long msk[RPB][5];          // layer-1 spike masks
    __shared__ float oacc[RPB][OUT_DIM];

    const int tid  = threadIdx.x;
    const int lane = tid & 63;
    const int wv   = __builtin_amdgcn_readfirstlane(tid >> 6);  // wave-uniform
    const int row0 = blockIdx.x * RPB;

    // ---- stage W1 into chunked LDS layout ----
    for (int idx = tid; idx < 3200; idx += 256) {
        int kc = idx % 10;
        int j  = idx / 10;
        float4 v;
        if (j < HID) v = *(const float4*)(W1 + j * IN_DIM + kc * 4);
        else         v = make_float4(0.f, 0.f, 0.f, 0.f);
        *(float4*)(w1c + (kc * 320 + j) * 4) = v;
    }
    for (int idx = tid; idx < RPB * 5; idx += 256) ((unsigned long long*)msk)[idx] = 0ull;
    for (int idx = tid; idx < RPB * OUT_DIM; idx += 256) ((float*)oacc)[idx] = 0.f;

    // per-lane biases for neurons j = lane + 64u (tail j>=300 -> 0)
    float b1h[5], b2r[5];
    sfor<5>([&](auto uc) {
        constexpr int u = decltype(uc)::v;
        int j = lane + 64 * u;
        b1h[u] = (j < HID) ? (b1[j] + bh[j]) : 0.f;
        b2r[u] = (j < HID) ? b2[j] : 0.f;
    });

    const float* WhT = ws;
    const float* W2T = ws + WS_W2T;
    const float* W3T = ws + WS_W3T;

    float v1[RPW][5], v2[RPW][5];
    sfor<RPW>([&](auto rc) {
        constexpr int r = decltype(rc)::v;
        sfor<5>([&](auto uc) {
            constexpr int u = decltype(uc)::v;
            v1[r][u] = 0.f; v2[r][u] = 0.f;
        });
    });

    __syncthreads();

    const unsigned long long TAILMASK = (1ull << 44) - 1ull;  // 44 valid lanes at u=4

    for (int t = 0; t < T_STEPS; ++t) {
        // wave-uniform base for this wave's 8 rows at step t -> s_load path
        const float* xt = x + ((size_t)t * BATCH + row0 + wv * RPW) * IN_DIM;

        // ---- h1 = x @ W1^T + (b1 + bh) ----
        float acc[RPW][5];
        sfor<RPW>([&](auto rc) {
            constexpr int r = decltype(rc)::v;
            sfor<5>([&](auto uc) {
                constexpr int u = decltype(uc)::v;
                acc[r][u] = b1h[u];
            });
        });

        sfor<10>([&](auto kcc) {
            constexpr int kc = decltype(kcc)::v;
            float4 w[5];
            sfor<5>([&](auto uc) {
                constexpr int u = decltype(uc)::v;
                w[u] = *(const float4*)(w1c + (kc * 320 + lane + 64 * u) * 4);
            });
            sfor<RPW>([&](auto rc) {
                constexpr int r = decltype(rc)::v;
                const float* xr = xt + r * IN_DIM + kc * 4;   // uniform
                float x0 = xr[0], x1 = xr[1], x2 = xr[2], x3 = xr[3];
                sfor<5>([&](auto uc) {
                    constexpr int u = decltype(uc)::v;
                    float a = acc[r][u];
                    a = fmaf(w[u].x, x0, a);
                    a = fmaf(w[u].y, x1, a);
                    a = fmaf(w[u].z, x2, a);
                    a = fmaf(w[u].w, x3, a);
                    acc[r][u] = a;
                });
            });
        });

        // ---- per-row LIF dynamics (acc doubles as cur: same FP add order) ----
        sfor<RPW>([&](auto rc) {
            constexpr int r = decltype(rc)::v;
            const int lr = wv * RPW + r;

            // recurrent input: y_{t-1} @ Wh^T (sparse column adds)
            sfor<5>([&](auto u2c) {
                constexpr int u2 = decltype(u2c)::v;
                unsigned long long m = msk[lr][u2];   // wave-uniform, wave-private
                while (m) {
                    int b = __builtin_ctzll(m);
                    m &= m - 1;
                    const float* wr = WhT + (u2 * 64 + b) * 320 + lane;
                    sfor<5>([&](auto uc) {
                        constexpr int u = decltype(uc)::v;
                        acc[r][u] += wr[64 * u];
                    });
                }
            });

            // LIF layer 1: v += (cur - v)/2 ; spike ; hard reset
            unsigned long long nm[5];
            sfor<5>([&](auto uc) {
                constexpr int u = decltype(uc)::v;
                float v = v1[r][u];
                v = v + (acc[r][u] - v) * 0.5f;
                bool s = (v >= 1.0f);
                v1[r][u] = s ? 0.f : v;
                nm[u] = __ballot(s);
            });
            nm[4] &= TAILMASK;

            if (lane == 0) {
                sfor<5>([&](auto uc) {
                    constexpr int u = decltype(uc)::v;
                    msk[lr][u] = nm[u];
                });
            }

            // layer 2: cur2 = y @ W2^T + b2 (sparse)
            float c2[5];
            sfor<5>([&](auto uc) {
                constexpr int u = decltype(uc)::v;
                c2[u] = b2r[u];
            });
            sfor<5>([&](auto u2c) {
                constexpr int u2 = decltype(u2c)::v;
                unsigned long long m = nm[u2];
                while (m) {
                    int b = __builtin_ctzll(m);
                    m &= m - 1;
                    const float* wr = W2T + (u2 * 64 + b) * 320 + lane;
                    sfor<5>([&](auto uc) {
                        constexpr int u = decltype(uc)::v;
                        c2[u] += wr[64 * u];
                    });
                }
            });

            // LIF layer 2 + output accumulation (s2 spikes are very rare)
            unsigned long long sm[5];
            sfor<5>([&](auto uc) {
                constexpr int u = decltype(uc)::v;
                float v = v2[r][u];
                v = v + (c2[u] - v) * 0.5f;
                bool s = (v >= 1.0f);
                v2[r][u] = s ? 0.f : v;
                sm[u] = __ballot(s);
            });
            sm[4] &= TAILMASK;
            sfor<5>([&](auto u2c) {
                constexpr int u2 = decltype(u2c)::v;
                unsigned long long m = sm[u2];
                while (m) {
                    int b = __builtin_ctzll(m);
                    m &= m - 1;
                    if (lane < OUT_DIM)
                        oacc[lr][lane] += W3T[(u2 * 64 + b) * OUT_DIM + lane];
                }
            });
        });
    }

    __syncthreads();

    // ---- epilogue: out = oacc + 101 * b3 ----
    for (int idx = tid; idx < RPB * OUT_DIM; idx += 256) {
        int r = idx / OUT_DIM, o = idx % OUT_DIM;
        out[(size_t)(row0 + r) * OUT_DIM + o] = oacc[r][o] + 101.0f * b3[o];
    }
}

extern "C" void kernel_launch(void* const* d_in, const int* in_sizes, int n_in,
                              void* d_out, int out_size, void* d_ws, size_t ws_size,
                              hipStream_t stream) {
    const float* x  = (const float*)d_in[0];
    const float* W1 = (const float*)d_in[1];
    const float* b1 = (const float*)d_in[2];
    const float* Wh = (const float*)d_in[3];
    const float* bh = (const float*)d_in[4];
    const float* W2 = (const float*)d_in[5];
    const float* b2 = (const float*)d_in[6];
    const float* W3 = (const float*)d_in[7];
    const float* b3 = (const float*)d_in[8];
    float* out = (float*)d_out;
    float* ws  = (float*)d_ws;

    prep_kernel<<<(195600 + 255) / 256, 256, 0, stream>>>(Wh, W2, W3, ws);
    snn_kernel<<<BATCH / RPB, 256, 0, stream>>>(x, W1, b1, bh, b2, b3, ws, out);
}